// Round 1
// baseline (247.351 us; speedup 1.0000x reference)
//
#include <hip/hip_runtime.h>

#define OBS 8
#define PREDL 12
#define NSTEP 19   // 8 obs + 11 pred-advance steps

typedef short short8 __attribute__((ext_vector_type(8)));
typedef float f32x16 __attribute__((ext_vector_type(16)));

__device__ __forceinline__ float sigm(float x) {
    // 1/(1+2^(-x*log2e))
    return __builtin_amdgcn_rcpf(1.0f + __builtin_amdgcn_exp2f(x * -1.4426950408889634f));
}
__device__ __forceinline__ float tanh_(float x) {
    // 2/(1+2^(-2x*log2e)) - 1
    return __builtin_amdgcn_rcpf(1.0f + __builtin_amdgcn_exp2f(x * -2.8853900817779268f)) * 2.0f - 1.0f;
}
__device__ __forceinline__ unsigned short f2bf(float f) {
    unsigned u = __builtin_bit_cast(unsigned, f);
    u += 0x7fffu + ((u >> 16) & 1u);   // RNE
    return (unsigned short)(u >> 16);
}

// One block = 128 batch rows, 4 waves x 32 rows. LDS: W_hh bf16 swizzled (128KB) + per-wave h staging (4x8KB).
__global__ __launch_bounds__(256, 1)
void lstm_persist(const float* __restrict__ traj_in, const float* __restrict__ traj_gt,
                  const float* __restrict__ W_ih, const float* __restrict__ W_hh,
                  const float* __restrict__ b_ih, const float* __restrict__ b_hh,
                  const float* __restrict__ W_last, const float* __restrict__ b_last,
                  float* __restrict__ out, float* __restrict__ ws)
{
    extern __shared__ char smem[];
    const int tid  = threadIdx.x;
    const int lane = tid & 63;
    const int wave = tid >> 6;
    const int l31  = lane & 31;
    const int half = lane >> 5;
    const int sw   = (lane & 7) << 4;         // read swizzle: row&7 == lane&7 for A and B reads
    const int b0   = blockIdx.x * 128;

    // ---- stage W_hh (f32 [512][128]) -> LDS bf16, row-major 256B rows, byte^=( (n&7)<<4 ) swizzle
    for (int it = 0; it < 128; ++it) {
        int idx = it * 256 + tid;             // float2-pair index, 64 pairs per row
        int n   = idx >> 6;
        int pr  = idx & 63;
        const float2 w = *(const float2*)(W_hh + n * 128 + pr * 2);
        unsigned pk = (unsigned)f2bf(w.x) | ((unsigned)f2bf(w.y) << 16);
        int bir = (pr * 4) ^ ((n & 7) << 4);
        *(unsigned*)(smem + n * 256 + bir) = pk;
    }
    // ---- zero h staging (32KB at 131072)
    {
        unsigned* hz = (unsigned*)(smem + 131072);
        for (int i = 0; i < 32; ++i) hz[tid + i * 256] = 0u;
    }
    __syncthreads();
    const int hB = 131072 + wave * 8192;      // wave-private h tile [32 rows][256B], same swizzle

    // ---- per-lane step-invariant constants (gate col n = gg*128 + cc*32 + l31)
    float bs[4][4], wiA[4][4], wiB[4][4];
    #pragma unroll
    for (int gg = 0; gg < 4; ++gg)
        #pragma unroll
        for (int cc = 0; cc < 4; ++cc) {
            int n = gg * 128 + cc * 32 + l31;
            bs[gg][cc] = b_ih[n] + b_hh[n];
            const float2 wi = *(const float2*)(W_ih + n * 2);
            wiA[gg][cc] = wi.x; wiB[gg][cc] = wi.y;
        }
    float wl0[4], wl1[4];
    #pragma unroll
    for (int cc = 0; cc < 4; ++cc) {
        wl0[cc] = W_last[cc * 32 + l31];
        wl1[cc] = W_last[128 + cc * 32 + l31];
    }
    const float bl0 = b_last[0], bl1 = b_last[1];

    float c_[4][16];
    #pragma unroll
    for (int cc = 0; cc < 4; ++cc)
        #pragma unroll
        for (int r = 0; r < 16; ++r) c_[cc][r] = 0.f;

    float hd0[16], hd1[16];                    // head output == next-step x (valid from t>=7)
    #pragma unroll
    for (int r = 0; r < 16; ++r) { hd0[r] = 0.f; hd1[r] = 0.f; }
    float lossAcc = 0.f;

    for (int t = 0; t < NSTEP; ++t) {
        const bool isObs    = (t < OBS);
        const bool needHead = (t >= OBS - 1);

        // ---- A fragments: h[l31 row][k], k = ks*16 + (lane>>5)*8 + e  -> b128 swizzled
        short8 a[8];
        #pragma unroll
        for (int ks = 0; ks < 8; ++ks)
            a[ks] = *(const short8*)(smem + hB + l31 * 256 + ((ks * 32 + half * 16) ^ sw));

        // ---- x per row-register
        float xr0[16], xr1[16];
        if (isObs) {
            const float2 xl = *(const float2*)(traj_in + ((size_t)(b0 + wave * 32 + l31) * OBS + t) * 2);
            #pragma unroll
            for (int r = 0; r < 16; ++r) {
                int src = (lane & 32) | ((r & 3) + 8 * (r >> 2) + 4 * half);
                xr0[r] = __shfl(xl.x, src, 64);
                xr1[r] = __shfl(xl.y, src, 64);
            }
        } else {
            #pragma unroll
            for (int r = 0; r < 16; ++r) { xr0[r] = hd0[r]; xr1[r] = hd1[r]; }
        }

        float hn0[16], hn1[16];
        #pragma unroll
        for (int r = 0; r < 16; ++r) { hn0[r] = 0.f; hn1[r] = 0.f; }

        // ---- main: 4 col-chunks of 32 h-cols; per chunk 4 gate groups x 8 K-slices
        #pragma unroll
        for (int cc = 0; cc < 4; ++cc) {
            f32x16 ac0{}, ac1{}, ac2{}, ac3{};
            #pragma unroll
            for (int ks = 0; ks < 8; ++ks) {
                const int bb = (ks * 32 + half * 16) ^ sw;
                const int n0 = cc * 32 + l31;                 // gg=0 row
                short8 f0 = *(const short8*)(smem + (n0)       * 256 + bb);
                short8 f1 = *(const short8*)(smem + (n0 + 128) * 256 + bb);
                short8 f2 = *(const short8*)(smem + (n0 + 256) * 256 + bb);
                short8 f3 = *(const short8*)(smem + (n0 + 384) * 256 + bb);
                ac0 = __builtin_amdgcn_mfma_f32_32x32x16_bf16(a[ks], f0, ac0, 0, 0, 0);
                ac1 = __builtin_amdgcn_mfma_f32_32x32x16_bf16(a[ks], f1, ac1, 0, 0, 0);
                ac2 = __builtin_amdgcn_mfma_f32_32x32x16_bf16(a[ks], f2, ac2, 0, 0, 0);
                ac3 = __builtin_amdgcn_mfma_f32_32x32x16_bf16(a[ks], f3, ac3, 0, 0, 0);
            }
            // ---- elementwise: D row = (r&3)+8*(r>>2)+4*half, col = cc*32+l31
            #pragma unroll
            for (int r = 0; r < 16; ++r) {
                float pi = ac0[r] + fmaf(xr1[r], wiB[0][cc], fmaf(xr0[r], wiA[0][cc], bs[0][cc]));
                float pf = ac1[r] + fmaf(xr1[r], wiB[1][cc], fmaf(xr0[r], wiA[1][cc], bs[1][cc]));
                float pg = ac2[r] + fmaf(xr1[r], wiB[2][cc], fmaf(xr0[r], wiA[2][cc], bs[2][cc]));
                float po = ac3[r] + fmaf(xr1[r], wiB[3][cc], fmaf(xr0[r], wiA[3][cc], bs[3][cc]));
                float iv = sigm(pi), fv = sigm(pf), gv = tanh_(pg), ov = sigm(po);
                float cv = fmaf(fv, c_[cc][r], iv * gv);
                c_[cc][r] = cv;
                float hv = ov * tanh_(cv);
                int row  = (r & 3) + 8 * (r >> 2) + 4 * half;
                int addr = hB + row * 256 + (((cc * 64) + l31 * 2) ^ ((row & 7) << 4));
                *(short*)(smem + addr) = (short)f2bf(hv);
                if (needHead) {
                    float rl = fmaxf(hv, 0.f);
                    hn0[r] = fmaf(rl, wl0[cc], hn0[r]);
                    hn1[r] = fmaf(rl, wl1[cc], hn1[r]);
                }
            }
        }

        if (needHead) {
            // butterfly-reduce over the 32 lanes of each half (cols of h)
            #pragma unroll
            for (int r = 0; r < 16; ++r) {
                #pragma unroll
                for (int s = 0; s < 5; ++s) {
                    hn0[r] += __shfl_xor(hn0[r], 1 << s, 64);
                    hn1[r] += __shfl_xor(hn1[r], 1 << s, 64);
                }
                hd0[r] = hn0[r] + bl0;
                hd1[r] = hn1[r] + bl1;
            }
            // emit prediction p = t-7 and accumulate squared error
            const int p = t - (OBS - 1);
            #pragma unroll
            for (int r = 0; r < 16; ++r) {
                int row = (r & 3) + 8 * (r >> 2) + 4 * half;
                size_t og = ((size_t)(b0 + wave * 32 + row) * PREDL + p) * 2;
                if (l31 == r) {
                    out[og] = hd0[r];
                    float d = hd0[r] - traj_gt[og];
                    lossAcc = fmaf(d, d, lossAcc);
                }
                if (l31 == r + 16) {
                    out[og + 1] = hd1[r];
                    float d = hd1[r] - traj_gt[og + 1];
                    lossAcc = fmaf(d, d, lossAcc);
                }
            }
        }
    }

    // ---- block loss partial (deterministic)
    __syncthreads();
    #pragma unroll
    for (int s = 1; s < 64; s <<= 1) lossAcc += __shfl_xor(lossAcc, s, 64);
    float* sred = (float*)smem;
    if (lane == 0) sred[wave] = lossAcc;
    __syncthreads();
    if (tid == 0) ws[blockIdx.x] = sred[0] + sred[1] + sred[2] + sred[3];
}

__global__ void loss_reduce(const float* __restrict__ ws, float* __restrict__ out,
                            int nblk, int nelem)
{
    __shared__ float sacc[4];
    int tid = threadIdx.x;
    float v = (tid < nblk) ? ws[tid] : 0.f;
    #pragma unroll
    for (int s = 1; s < 64; s <<= 1) v += __shfl_xor(v, s, 64);
    if ((tid & 63) == 0) sacc[tid >> 6] = v;
    __syncthreads();
    if (tid == 0) out[nelem] = (sacc[0] + sacc[1] + sacc[2] + sacc[3]) / (float)nelem;
}

extern "C" void kernel_launch(void* const* d_in, const int* in_sizes, int n_in,
                              void* d_out, int out_size, void* d_ws, size_t ws_size,
                              hipStream_t stream)
{
    const float* traj_in = (const float*)d_in[0];
    const float* traj_gt = (const float*)d_in[1];
    const float* W_ih    = (const float*)d_in[2];
    const float* W_hh    = (const float*)d_in[3];
    const float* b_ih    = (const float*)d_in[4];
    const float* b_hh    = (const float*)d_in[5];
    const float* W_last  = (const float*)d_in[6];
    const float* b_last  = (const float*)d_in[7];
    float* out = (float*)d_out;
    float* ws  = (float*)d_ws;

    const int B      = in_sizes[0] / (OBS * 2);   // 32768
    const int blocks = B / 128;                    // 256
    const size_t shmem = 131072 + 4 * 8192;        // 160 KB

    lstm_persist<<<blocks, 256, shmem, stream>>>(traj_in, traj_gt, W_ih, W_hh,
                                                 b_ih, b_hh, W_last, b_last, out, ws);
    loss_reduce<<<1, 256, 0, stream>>>(ws, out, blocks, out_size - 1);
}